// Round 3
// baseline (290.489 us; speedup 1.0000x reference)
//
#include <hip/hip_runtime.h>
#include <math.h>

#define BINS 10
#define HSTRIDE 11          // 10 bins padded to 11 (gcd(11,32)=1 -> spread banks)
#define K1_BLOCKS 1024
#define K1_THREADS 512

// Per-element math: xs = label ? -x : x ; p_norm = sigmoid(xs) ;
// bce = softplus(xs) = max(xs,0) + log(1 + exp(-|xs|)).
// Histogram update = 2 fire-and-forget LDS float atomics (ds_add_f32):
// no return value -> no dependency chain, executes on the LDS pipe
// concurrently with VALU.
__device__ __forceinline__ void ghm_elem(int y, float x, float w,
                                         float* __restrict__ cbase,
                                         float* __restrict__ sbase) {
    float xs = (y == 1) ? -x : x;
    float e  = __expf(-fabsf(xs));              // exp(-|xs|) in (0,1]
    float d  = 1.0f + e;
    float r  = __builtin_amdgcn_rcpf(d);        // raw v_rcp_f32 (1ulp, fine for binning)
    float pn = (xs >= 0.0f) ? r : e * r;        // sigmoid(xs) == p_norm
    int bin  = (int)(pn * 10.0f);               // pn in (0,1) -> trunc == floor
    bin = bin > (BINS - 1) ? (BINS - 1) : bin;
    float bce   = fmaxf(xs, 0.0f) + __logf(d);  // log(d) == log1p(e)
    float valid = (w > 0.0f) ? 1.0f : 0.0f;
    atomicAdd(cbase + bin, valid);              // ds_add_f32, no-return
    atomicAdd(sbase + bin, bce * valid);
}

// Kernel 1: block-shared 64-copy LDS histogram (copy = lane id, shared across
// the block's 8 waves via atomics), 8 elements per thread per iteration.
// partial layout in d_ws: rows 0..9 = counts, rows 10..19 = bce sums,
// K1_BLOCKS cols.
__global__ __launch_bounds__(K1_THREADS) void ghm_partial(
    const int*   __restrict__ labels,
    const float* __restrict__ logits,
    const float* __restrict__ weights,
    float*       __restrict__ partial,
    int n8, int n)
{
    __shared__ float h_cnt[64 * HSTRIDE];
    __shared__ float h_sum[64 * HSTRIDE];
    const int tid  = threadIdx.x;
    const int lane = tid & 63;

    for (int i = tid; i < 64 * HSTRIDE; i += K1_THREADS) {
        h_cnt[i] = 0.0f;
        h_sum[i] = 0.0f;
    }
    __syncthreads();

    float* cbase = &h_cnt[lane * HSTRIDE];
    float* sbase = &h_sum[lane * HSTRIDE];

    const int4*   lab4 = (const int4*)labels;
    const float4* log4 = (const float4*)logits;
    const float4* w4   = (const float4*)weights;

    const int stride = gridDim.x * blockDim.x;
    for (int i = blockIdx.x * blockDim.x + tid; i < n8; i += stride) {
        const int b0 = i * 2;
        // 6 independent dwordx4 loads in flight (96 B/lane of MLP)
        int4   lb0 = lab4[b0],  lb1 = lab4[b0 + 1];
        float4 xv0 = log4[b0],  xv1 = log4[b0 + 1];
        float4 wv0 = w4[b0],    wv1 = w4[b0 + 1];

        ghm_elem(lb0.x, xv0.x, wv0.x, cbase, sbase);
        ghm_elem(lb0.y, xv0.y, wv0.y, cbase, sbase);
        ghm_elem(lb0.z, xv0.z, wv0.z, cbase, sbase);
        ghm_elem(lb0.w, xv0.w, wv0.w, cbase, sbase);
        ghm_elem(lb1.x, xv1.x, wv1.x, cbase, sbase);
        ghm_elem(lb1.y, xv1.y, wv1.y, cbase, sbase);
        ghm_elem(lb1.z, xv1.z, wv1.z, cbase, sbase);
        ghm_elem(lb1.w, xv1.w, wv1.w, cbase, sbase);
    }

    // scalar tail (n % 8), block 0 only (n divisible by 8 here; kept for safety)
    const int rem_start = n8 * 8;
    if (blockIdx.x == 0 && tid < (n - rem_start)) {
        const int idx = rem_start + tid;
        ghm_elem(labels[idx], logits[idx], weights[idx], cbase, sbase);
    }

    __syncthreads();

    // wave 0 reduces the 64 histogram copies
    if (tid < 64) {
        float c[BINS], s[BINS];
        #pragma unroll
        for (int b = 0; b < BINS; ++b) {
            c[b] = h_cnt[tid * HSTRIDE + b];
            s[b] = h_sum[tid * HSTRIDE + b];
        }
        #pragma unroll
        for (int off = 32; off > 0; off >>= 1) {
            #pragma unroll
            for (int b = 0; b < BINS; ++b) {
                c[b] += __shfl_down(c[b], off);
                s[b] += __shfl_down(s[b], off);
            }
        }
        if (tid == 0) {
            #pragma unroll
            for (int b = 0; b < BINS; ++b) {
                partial[b * K1_BLOCKS + blockIdx.x]          = c[b];
                partial[(BINS + b) * K1_BLOCKS + blockIdx.x] = s[b];
            }
        }
    }
}

// Kernel 2: reduce K1_BLOCKS partial columns, finalize scalar.
__global__ __launch_bounds__(1024) void ghm_final(
    const float* __restrict__ partial, float* __restrict__ out)
{
    const int tid = threadIdx.x;
    float acc[2 * BINS];
    #pragma unroll
    for (int b = 0; b < 2 * BINS; ++b)
        acc[b] = partial[b * K1_BLOCKS + tid];   // coalesced row loads

    #pragma unroll
    for (int off = 32; off > 0; off >>= 1) {
        #pragma unroll
        for (int b = 0; b < 2 * BINS; ++b)
            acc[b] += __shfl_down(acc[b], off);
    }

    __shared__ float red[16][2 * BINS];
    const int wave = tid >> 6, lane = tid & 63;
    if (lane == 0) {
        #pragma unroll
        for (int b = 0; b < 2 * BINS; ++b) red[wave][b] = acc[b];
    }
    __syncthreads();

    if (tid == 0) {
        float cnt[BINS], s[BINS];
        #pragma unroll
        for (int b = 0; b < BINS; ++b) { cnt[b] = 0.0f; s[b] = 0.0f; }
        for (int wv = 0; wv < 16; ++wv) {
            #pragma unroll
            for (int b = 0; b < BINS; ++b) {
                cnt[b] += red[wv][b];
                s[b]   += red[wv][BINS + b];
            }
        }
        float n = 0.0f, res = 0.0f;
        #pragma unroll
        for (int b = 0; b < BINS; ++b) {
            if (cnt[b] > 0.0f) {
                n   += 1.0f;
                res += s[b] / fmaxf(cnt[b], 1.0f);
            }
        }
        if (n > 0.0f) res /= n;   // total_num cancels exactly in the algebra
        out[0] = res;
    }
}

extern "C" void kernel_launch(void* const* d_in, const int* in_sizes, int n_in,
                              void* d_out, int out_size, void* d_ws, size_t ws_size,
                              hipStream_t stream) {
    const int*   labels  = (const int*)d_in[0];
    const float* logits  = (const float*)d_in[1];
    const float* weights = (const float*)d_in[2];
    float* out     = (float*)d_out;
    float* partial = (float*)d_ws;   // needs 2*BINS*K1_BLOCKS*4 = 80 KiB

    const int n  = in_sizes[0];
    const int n8 = n / 8;

    ghm_partial<<<K1_BLOCKS, K1_THREADS, 0, stream>>>(labels, logits, weights, partial, n8, n);
    ghm_final<<<1, 1024, 0, stream>>>(partial, out);
}